// Round 1
// baseline (69.324 us; speedup 1.0000x reference)
//
#include <hip/hip_runtime.h>

#define S_TOTAL   1500000
#define P_POSES   32
#define A_ATOMS   4096
#define T_HASH    1048576
#define EPSF      1e-8f

__global__ void zero_out_kernel(float* __restrict__ out) {
    int i = threadIdx.x;
    if (i < P_POSES) out[i] = 0.0f;
}

__global__ __launch_bounds__(256) void cartbonded_kernel(
    const float* __restrict__ coords,       // [P, A, 3]
    const float* __restrict__ hv,           // [T, 3]
    const int4*  __restrict__ atoms,        // [S, 4]
    const int*   __restrict__ pose,         // [S]
    const int*   __restrict__ uids,         // [P, A]
    float*       __restrict__ out,          // [P]
    int S)
{
    __shared__ float bins[P_POSES];
    for (int i = threadIdx.x; i < P_POSES; i += blockDim.x) bins[i] = 0.0f;
    __syncthreads();

    const int stride = gridDim.x * blockDim.x;
    for (int s = blockIdx.x * blockDim.x + threadIdx.x; s < S; s += stride) {
        const int4 a = atoms[s];
        const int  p = pose[s];

        const bool v0 = a.x >= 0, v1 = a.y >= 0, v2 = a.z >= 0, v3 = a.w >= 0;
        const int  i0 = v0 ? a.x : 0;
        const int  i1 = v1 ? a.y : 0;
        const int  i2 = v2 ? a.z : 0;
        const int  i3 = v3 ? a.w : 0;
        const int  nv = (int)v0 + (int)v1 + (int)v2 + (int)v3;

        // hash key: sum of valid uids (uint32) mod 2^20
        const int* __restrict__ urow = uids + p * A_ATOMS;
        unsigned int key = 0u;
        key += v0 ? (unsigned int)urow[i0] : 0u;
        key += v1 ? (unsigned int)urow[i1] : 0u;
        key += v2 ? (unsigned int)urow[i2] : 0u;
        key += v3 ? (unsigned int)urow[i3] : 0u;
        key &= (unsigned int)(T_HASH - 1);

        const float* __restrict__ hp = hv + (size_t)key * 3;
        const float K      = hp[0];
        const float x0     = hp[1];
        const float period = hp[2];

        const float* __restrict__ crow = coords + (size_t)p * (A_ATOMS * 3);
        const float p0x = crow[i0*3+0], p0y = crow[i0*3+1], p0z = crow[i0*3+2];
        const float p1x = crow[i1*3+0], p1y = crow[i1*3+1], p1z = crow[i1*3+2];
        const float p2x = crow[i2*3+0], p2y = crow[i2*3+1], p2z = crow[i2*3+2];
        const float p3x = crow[i3*3+0], p3y = crow[i3*3+1], p3z = crow[i3*3+2];

        // ---- bond: K*(|p1-p0| - x0)^2
        const float dbx = p1x - p0x, dby = p1y - p0y, dbz = p1z - p0z;
        const float d  = sqrtf(dbx*dbx + dby*dby + dbz*dbz + EPSF);
        const float db = d - x0;
        const float e_bond = K * db * db;

        // ---- angle: K*(acos(clip(cos)) - x0)^2 with u=p0-p1, v=p2-p1
        const float ux = p0x - p1x, uy = p0y - p1y, uz = p0z - p1z;
        const float vx = p2x - p1x, vy = p2y - p1y, vz = p2z - p1z;
        const float uv  = ux*vx + uy*vy + uz*vz;
        const float uu  = ux*ux + uy*uy + uz*uz;
        const float vv  = vx*vx + vy*vy + vz*vz;
        float cosang = uv / (sqrtf(uu + EPSF) * sqrtf(vv + EPSF));
        cosang = fminf(fmaxf(cosang, -0.999999f), 0.999999f);
        const float theta = acosf(cosang);
        const float da = theta - x0;
        const float e_angle = K * da * da;

        // ---- torsion
        const float b1x = p1x - p0x, b1y = p1y - p0y, b1z = p1z - p0z;
        const float b2x = p2x - p1x, b2y = p2y - p1y, b2z = p2z - p1z;
        const float b3x = p3x - p2x, b3y = p3y - p2y, b3z = p3z - p2z;
        // n1 = b1 x b2 ; n2 = b2 x b3
        const float n1x = b1y*b2z - b1z*b2y;
        const float n1y = b1z*b2x - b1x*b2z;
        const float n1z = b1x*b2y - b1y*b2x;
        const float n2x = b2y*b3z - b2z*b3y;
        const float n2y = b2z*b3x - b2x*b3z;
        const float n2z = b2x*b3y - b2y*b3x;
        const float b2inv = 1.0f / sqrtf(b2x*b2x + b2y*b2y + b2z*b2z + EPSF);
        const float bnx = b2x * b2inv, bny = b2y * b2inv, bnz = b2z * b2inv;
        // m1 = n1 x b2n
        const float m1x = n1y*bnz - n1z*bny;
        const float m1y = n1z*bnx - n1x*bnz;
        const float m1z = n1x*bny - n1y*bnx;
        const float sy = m1x*n2x + m1y*n2y + m1z*n2z;
        const float sx = n1x*n2x + n1y*n2y + n1z*n2z + EPSF;
        const float phi = atan2f(sy, sx);
        const float e_tors = K * (1.0f + cosf(period * phi - x0));

        const float e = (nv == 2) ? e_bond : ((nv == 3) ? e_angle : e_tors);
        atomicAdd(&bins[p], e);
    }

    __syncthreads();
    if (threadIdx.x < P_POSES) {
        const float b = bins[threadIdx.x];
        if (b != 0.0f) atomicAdd(&out[threadIdx.x], b);
    }
}

extern "C" void kernel_launch(void* const* d_in, const int* in_sizes, int n_in,
                              void* d_out, int out_size, void* d_ws, size_t ws_size,
                              hipStream_t stream) {
    const float* coords = (const float*)d_in[0];
    const float* hv     = (const float*)d_in[1];
    const int4*  atoms  = (const int4*)d_in[2];
    const int*   pose   = (const int*)d_in[3];
    const int*   uids   = (const int*)d_in[4];
    float* out = (float*)d_out;

    const int S = in_sizes[3];   // subgraph_pose has S elements

    zero_out_kernel<<<1, 64, 0, stream>>>(out);

    const int block = 256;
    const int grid  = 2048;
    cartbonded_kernel<<<grid, block, 0, stream>>>(coords, hv, atoms, pose, uids, out, S);
}